// Round 8
// baseline (708.806 us; speedup 1.0000x reference)
//
#include <hip/hip_runtime.h>

#define N_NODES 100000
#define N_EDGES 1600000
#define D 128
#define SCAN_BLOCKS 391   // ceil(N_NODES / 256)
#define NBUCK 98          // ceil(N_NODES / 1024), bucket = dst >> 10

typedef __attribute__((ext_vector_type(8))) short bf16x8;
typedef __attribute__((ext_vector_type(4))) float f32x4;
typedef unsigned long long u64;

__device__ __forceinline__ float b2f_lo(unsigned int u) {
    return __builtin_bit_cast(float, u << 16);
}
__device__ __forceinline__ float b2f_hi(unsigned int u) {
    return __builtin_bit_cast(float, u & 0xFFFF0000u);
}
__device__ __forceinline__ unsigned short f2b(float f) {
    unsigned int u = __builtin_bit_cast(unsigned int, f);
    u += 0x7FFFu + ((u >> 16) & 1u);
    return (unsigned short)(u >> 16);
}

// ---------------- prep: zero scratch + convert weights + convert x, one dispatch ----------------
// Scratch counters (deg/cnt2/bcur) live in d_out (dead until the final MLP overwrites
// all of d_out), so prep can run first and nothing aliases xb/P/Wt later.

__global__ __launch_bounds__(256) void prep_kernel(
    const float* __restrict__ x, unsigned short* __restrict__ xb,
    const float* __restrict__ W0, const float* __restrict__ W1_, const float* __restrict__ W2_,
    const float* __restrict__ W3, const float* __restrict__ W4, const float* __restrict__ W5,
    unsigned short* __restrict__ T0, unsigned short* __restrict__ T1_,
    unsigned short* __restrict__ T2_, unsigned short* __restrict__ T3,
    unsigned short* __restrict__ T4, unsigned short* __restrict__ T5,
    uint4* __restrict__ dob4) {
    int blk = blockIdx.x;
    if (blk < 384) {
        const float* W;
        unsigned short* T;
        switch (blk >> 6) {
            case 0: W = W0; T = T0; break;
            case 1: W = W1_; T = T1_; break;
            case 2: W = W2_; T = T2_; break;
            case 3: W = W3; T = T3; break;
            case 4: W = W4; T = T4; break;
            default: W = W5; T = T5; break;
        }
        int i = (blk & 63) * 256 + threadIdx.x;   // 0..16383
        int k = i >> 7, n = i & 127;
        T[n * 128 + k] = f2b(W[i]);               // [k][n] fp32 -> [n][k] bf16
    } else if (blk < 12884) {
        int i = (blk - 384) * 256 + threadIdx.x;  // float4 chunks, 3200000 total
        if (i < 3200000) {
            float4 v = ((const float4*)x)[i];
            ushort4 o;
            o.x = f2b(v.x); o.y = f2b(v.y); o.z = f2b(v.z); o.w = f2b(v.w);
            ((ushort4*)xb)[i] = o;
        }
    } else {
        int i = (blk - 12884) * 256 + threadIdx.x;  // zero d_out scratch head [0, 806144)
        if (i < 50384) {
            uint4 z = {0u, 0u, 0u, 0u};
            dob4[i] = z;
        }
    }
}

// ---------------- CSR build ----------------

__global__ void hist_kernel(const int* __restrict__ dst, int* __restrict__ deg, int n) {
    int i = blockIdx.x * blockDim.x + threadIdx.x;
    if (i < n) atomicAdd(&deg[dst[i]], 1);
}

__global__ __launch_bounds__(256) void block_sum_kernel(const int* __restrict__ deg,
                                                        int* __restrict__ bsum) {
    __shared__ int s[256];
    int i = blockIdx.x * 256 + threadIdx.x;
    int v = (i < N_NODES) ? deg[i] : 0;
    s[threadIdx.x] = v;
    __syncthreads();
#pragma unroll
    for (int d = 128; d > 0; d >>= 1) {
        if (threadIdx.x < d) s[threadIdx.x] += s[threadIdx.x + d];
        __syncthreads();
    }
    if (threadIdx.x == 0) bsum[blockIdx.x] = s[0];
}

__global__ __launch_bounds__(512) void scan_bsum_kernel(const int* __restrict__ bsum,
                                                        int* __restrict__ bpref,
                                                        int* __restrict__ off) {
    __shared__ int s[512];
    int tid = threadIdx.x;
    int v = (tid < SCAN_BLOCKS) ? bsum[tid] : 0;
    s[tid] = v;
    __syncthreads();
#pragma unroll
    for (int d = 1; d < 512; d <<= 1) {
        int t = (tid >= d) ? s[tid - d] : 0;
        __syncthreads();
        s[tid] += t;
        __syncthreads();
    }
    if (tid < SCAN_BLOCKS) bpref[tid] = s[tid] - v;   // exclusive
    if (tid == 0) off[N_NODES] = N_EDGES;
}

__global__ __launch_bounds__(256) void block_scan_kernel(const int* __restrict__ deg,
                                                         const int* __restrict__ bpref,
                                                         int* __restrict__ off) {
    __shared__ int s[256];
    int i = blockIdx.x * 256 + threadIdx.x;
    int tid = threadIdx.x;
    int v = (i < N_NODES) ? deg[i] : 0;
    s[tid] = v;
    __syncthreads();
#pragma unroll
    for (int d = 1; d < 256; d <<= 1) {
        int t = (tid >= d) ? s[tid - d] : 0;
        __syncthreads();
        s[tid] += t;
        __syncthreads();
    }
    if (i < N_NODES) off[i] = bpref[blockIdx.x] + s[tid] - v;   // exclusive
}

// Bin edges into bucket-ordered packed (dst<<32|src) slabs. Slab base = off[b<<10].
__global__ __launch_bounds__(256) void bin_kernel(const int* __restrict__ src,
                                                  const int* __restrict__ dst,
                                                  const int* __restrict__ off,
                                                  int* __restrict__ bcur,
                                                  u64* __restrict__ ebuf) {
    __shared__ int h[NBUCK];
    __shared__ int base[NBUCK];
    int tid = threadIdx.x;
    if (tid < NBUCK) h[tid] = 0;
    __syncthreads();
    int e0 = blockIdx.x * 2048;
    int myd[8], mys[8];
#pragma unroll
    for (int i = 0; i < 8; i++) {
        int e = e0 + tid + i * 256;
        int dv = (e < N_EDGES) ? dst[e] : -1;
        myd[i] = dv;
        mys[i] = (e < N_EDGES) ? src[e] : 0;
        if (dv >= 0) atomicAdd(&h[dv >> 10], 1);
    }
    __syncthreads();
    if (tid < NBUCK) {
        int c = h[tid];
        base[tid] = (c > 0) ? (off[tid << 10] + atomicAdd(&bcur[tid], c)) : 0;
        h[tid] = 0;
    }
    __syncthreads();
#pragma unroll
    for (int i = 0; i < 8; i++) {
        int dv = myd[i];
        if (dv >= 0) {
            int b = dv >> 10;
            int p = base[b] + atomicAdd(&h[b], 1);
            ebuf[p] = ((u64)(unsigned int)dv << 32) | (unsigned int)mys[i];
        }
    }
}

// Scatter with approximate src-ordering: stage 2048 edges in LDS, emit in 8 src-range
// passes. Ranks per node become ~ascending in src (12.5k-node bands), so the agg's
// gather sweeps a shrinking working-set band -> better L2 hit rate. Any per-node
// order is a valid CSR; ordering is a locality hint only.
__global__ __launch_bounds__(256) void scatter2_kernel(const u64* __restrict__ ebuf,
                                                       const int* __restrict__ off,
                                                       int* __restrict__ cnt,
                                                       int* __restrict__ csr) {
    __shared__ u64 se[2048];
    int tid = threadIdx.x;
    int base = blockIdx.x * 2048;
#pragma unroll
    for (int i = 0; i < 8; i++) {
        int e = base + tid + i * 256;
        se[tid + i * 256] = (e < N_EDGES) ? ebuf[e] : ~0ull;
    }
    __syncthreads();
    for (int p = 0; p < 8; p++) {
        int lo = p * 12500, hi = lo + 12500;
#pragma unroll
        for (int i = 0; i < 8; i++) {
            u64 e = se[tid + i * 256];
            if (e == ~0ull) continue;
            int sv = (int)(e & 0xFFFFFFFFu);
            if (sv >= lo && sv < hi) {
                int dv = (int)(e >> 32);
                int pos = off[dv] + atomicAdd(&cnt[dv], 1);
                csr[pos] = sv;
            }
        }
    }
}

// ---------------- aggregation: t[i] = x[i] + sum_{j in N_in(i)} x[j]  (bf16 in/out) ----------------

__global__ __launch_bounds__(256) void agg_bf16(const unsigned int* __restrict__ xb,
                                                const int* __restrict__ off,
                                                const int* __restrict__ csr,
                                                unsigned int* __restrict__ t) {
    int node = blockIdx.x * 4 + (threadIdx.x >> 6);
    if (node >= N_NODES) return;
    int lane = threadIdx.x & 63;
    unsigned int v = xb[(size_t)node * 64 + lane];
    float ax = b2f_lo(v), ay = b2f_hi(v);
    int e = off[node + 1];
    int k = off[node];
    for (; k + 4 <= e; k += 4) {
        int n0 = csr[k + 0], n1 = csr[k + 1], n2 = csr[k + 2], n3 = csr[k + 3];
        unsigned int g0 = xb[(size_t)n0 * 64 + lane];
        unsigned int g1 = xb[(size_t)n1 * 64 + lane];
        unsigned int g2 = xb[(size_t)n2 * 64 + lane];
        unsigned int g3 = xb[(size_t)n3 * 64 + lane];
        ax += b2f_lo(g0) + b2f_lo(g1) + b2f_lo(g2) + b2f_lo(g3);
        ay += b2f_hi(g0) + b2f_hi(g1) + b2f_hi(g2) + b2f_hi(g3);
    }
    for (; k < e; k++) {
        unsigned int g = xb[(size_t)csr[k] * 64 + lane];
        ax += b2f_lo(g);
        ay += b2f_hi(g);
    }
    t[(size_t)node * 64 + lane] = (unsigned int)f2b(ax) | ((unsigned int)f2b(ay) << 16);
}

// ---------------- fused MLP: y = relu(relu(t @ W1 + b1) @ W2 + b2) ----------------

template <bool OUT_F32>
__global__ __launch_bounds__(256) void mlp_mfma(const unsigned short* __restrict__ A,
                                                const unsigned short* __restrict__ W1t,
                                                const float* __restrict__ bias1,
                                                const unsigned short* __restrict__ W2t,
                                                const float* __restrict__ bias2,
                                                void* __restrict__ out) {
    constexpr int WB = OUT_F32 ? 8448 : 4352;
    __shared__ char smem[4 * WB];
    int tid = threadIdx.x;
    int wave = tid >> 6, lane = tid & 63;
    int quad = lane >> 4, mr = lane & 15;
    int m_base = blockIdx.x * 64 + wave * 16;
    int m = m_base + mr;
    if (m >= N_NODES) m = N_NODES - 1;

    unsigned short* ust = (unsigned short*)(smem + wave * WB);   // 16 x 136 shorts

    // ---- GEMM1: u = relu(t @ W1 + b1) ----
    bf16x8 a[4];
#pragma unroll
    for (int kc = 0; kc < 4; kc++)
        a[kc] = *(const bf16x8*)(A + (size_t)m * D + kc * 32 + quad * 8);

    f32x4 acc[8];
#pragma unroll
    for (int nt = 0; nt < 8; nt++) acc[nt] = (f32x4)0.0f;
#pragma unroll
    for (int nt = 0; nt < 8; nt++) {
        const unsigned short* wp = W1t + (size_t)(nt * 16 + mr) * D + quad * 8;
#pragma unroll
        for (int kc = 0; kc < 4; kc++) {
            bf16x8 b = *(const bf16x8*)(wp + kc * 32);
            acc[nt] = __builtin_amdgcn_mfma_f32_16x16x32_bf16(a[kc], b, acc[nt], 0, 0, 0);
        }
    }
    // C layout: col(n) = mr, row(m in strip) = quad*4 + r
#pragma unroll
    for (int nt = 0; nt < 8; nt++) {
        float bv = bias1[nt * 16 + mr];
#pragma unroll
        for (int r = 0; r < 4; r++)
            ust[(quad * 4 + r) * 136 + nt * 16 + mr] = f2b(fmaxf(acc[nt][r] + bv, 0.0f));
    }

    // ---- GEMM2: y = relu(u @ W2 + b2) ----
#pragma unroll
    for (int kc = 0; kc < 4; kc++)
        a[kc] = *(const bf16x8*)&ust[mr * 136 + kc * 32 + quad * 8];
#pragma unroll
    for (int nt = 0; nt < 8; nt++) acc[nt] = (f32x4)0.0f;
#pragma unroll
    for (int nt = 0; nt < 8; nt++) {
        const unsigned short* wp = W2t + (size_t)(nt * 16 + mr) * D + quad * 8;
#pragma unroll
        for (int kc = 0; kc < 4; kc++) {
            bf16x8 b = *(const bf16x8*)(wp + kc * 32);
            acc[nt] = __builtin_amdgcn_mfma_f32_16x16x32_bf16(a[kc], b, acc[nt], 0, 0, 0);
        }
    }

    // ---- epilogue: stage strip in LDS, coalesced store ----
    if (OUT_F32) {
        float* st = (float*)ust;   // 16 x 132 f32 = 8448 B
        const int S = 132;
#pragma unroll
        for (int nt = 0; nt < 8; nt++) {
            float bv = bias2[nt * 16 + mr];
#pragma unroll
            for (int r = 0; r < 4; r++)
                st[(quad * 4 + r) * S + nt * 16 + mr] = fmaxf(acc[nt][r] + bv, 0.0f);
        }
        float* op = (float*)out;
#pragma unroll
        for (int it = 0; it < 8; it++) {
            int linear = lane + it * 64;
            int row = linear >> 5, col = (linear & 31) << 2;
            int gm = m_base + row;
            if (gm < N_NODES) {
                float4 val = *(float4*)&st[row * S + col];
                *(float4*)(op + (size_t)gm * D + col) = val;
            }
        }
    } else {
        unsigned short* st = ust;  // reuse u-strip (A2 frags consumed before overwrite)
        const int S = 136;
#pragma unroll
        for (int nt = 0; nt < 8; nt++) {
            float bv = bias2[nt * 16 + mr];
#pragma unroll
            for (int r = 0; r < 4; r++)
                st[(quad * 4 + r) * S + nt * 16 + mr] = f2b(fmaxf(acc[nt][r] + bv, 0.0f));
        }
        unsigned short* op = (unsigned short*)out;
#pragma unroll
        for (int it = 0; it < 4; it++) {
            int linear = lane + it * 64;
            int row = linear >> 4, col = (linear & 15) << 3;
            int gm = m_base + row;
            if (gm < N_NODES) {
                uint4 val = *(uint4*)&st[row * S + col];
                *(uint4*)(op + (size_t)gm * D + col) = val;
            }
        }
    }
}

// ---------------- launch ----------------

extern "C" void kernel_launch(void* const* d_in, const int* in_sizes, int n_in,
                              void* d_out, int out_size, void* d_ws, size_t ws_size,
                              hipStream_t stream) {
    const float* x = (const float*)d_in[0];
    const int* ei = (const int*)d_in[1];
    const int* srcv = ei;
    const int* dstv = ei + N_EDGES;
    const float* W1[3] = {(const float*)d_in[2], (const float*)d_in[6], (const float*)d_in[10]};
    const float* b1[3] = {(const float*)d_in[3], (const float*)d_in[7], (const float*)d_in[11]};
    const float* W2[3] = {(const float*)d_in[4], (const float*)d_in[8], (const float*)d_in[12]};
    const float* b2[3] = {(const float*)d_in[5], (const float*)d_in[9], (const float*)d_in[13]};

    // ws layout (high-water 58400256, proven since R1):
    char* ws = (char*)d_ws;
    int* off = (int*)ws;                                    // (N+1) ints
    unsigned short* Wt[6];                                  // 6 x 32KB @ 400128 (stable all run)
    for (int i = 0; i < 6; i++) Wt[i] = (unsigned short*)(ws + 400128 + i * 32768);
    int* csr = (int*)(ws + 800256);                         // E ints (ends 7200256)
    unsigned short* xb = (unsigned short*)(ws + 7200256);   // N*D bf16 (ends 32800256)
    unsigned short* P  = (unsigned short*)(ws + 32800256);  // N*D bf16 (ends 58400256)

    // d_out scratch (dead by the final MLP, which overwrites all of d_out):
    char* dob = (char*)d_out;
    int* deg   = (int*)(dob + 4096);        // N ints  [4096, 404096)
    int* cnt2  = (int*)(dob + 404096);      // N ints  [404096, 804096)
    int* bcur  = (int*)(dob + 804096);      // NBUCK ints
    int* bsum  = (int*)(dob + 806912);      // SCAN_BLOCKS ints
    int* bpref = (int*)(dob + 808960);      // SCAN_BLOCKS ints (end ~810524)
    u64* ebuf  = (u64*)(dob + 1048576);     // E u64 = 12.8MB [1MB, 13.8MB)

    // --- prep: zero d_out scratch head + convert weights + convert x (one dispatch) ---
    prep_kernel<<<13082, 256, 0, stream>>>(
        x, xb,
        W1[0], W2[0], W1[1], W2[1], W1[2], W2[2],
        Wt[0], Wt[1], Wt[2], Wt[3], Wt[4], Wt[5],
        (uint4*)dob);

    // --- CSR build (once; reused by all 3 layers) ---
    hist_kernel<<<(N_EDGES + 255) / 256, 256, 0, stream>>>(dstv, deg, N_EDGES);
    block_sum_kernel<<<SCAN_BLOCKS, 256, 0, stream>>>(deg, bsum);
    scan_bsum_kernel<<<1, 512, 0, stream>>>(bsum, bpref, off);
    block_scan_kernel<<<SCAN_BLOCKS, 256, 0, stream>>>(deg, bpref, off);
    bin_kernel<<<782, 256, 0, stream>>>(srcv, dstv, off, bcur, ebuf);
    scatter2_kernel<<<782, 256, 0, stream>>>(ebuf, off, cnt2, csr);

    const int agg_grid = 25000;                        // 4 nodes/block
    const int mlp_grid = (N_NODES + 63) / 64;          // 1563

    // layer 0: agg xb->P, mlp P->xb
    agg_bf16<<<agg_grid, 256, 0, stream>>>((const unsigned int*)xb, off, csr, (unsigned int*)P);
    mlp_mfma<false><<<mlp_grid, 256, 0, stream>>>(P, Wt[0], b1[0], Wt[1], b2[0], xb);
    // layer 1
    agg_bf16<<<agg_grid, 256, 0, stream>>>((const unsigned int*)xb, off, csr, (unsigned int*)P);
    mlp_mfma<false><<<mlp_grid, 256, 0, stream>>>(P, Wt[2], b1[1], Wt[3], b2[1], xb);
    // layer 2
    agg_bf16<<<agg_grid, 256, 0, stream>>>((const unsigned int*)xb, off, csr, (unsigned int*)P);
    mlp_mfma<true><<<mlp_grid, 256, 0, stream>>>(P, Wt[4], b1[2], Wt[5], b2[2], d_out);
}

// Round 9
// 626.132 us; speedup vs baseline: 1.1320x; 1.1320x over previous
//
#include <hip/hip_runtime.h>

#define N_NODES 100000
#define N_EDGES 1600000
#define D 128
#define SCAN_BLOCKS 391   // ceil(N_NODES / 256)
#define NBUCK 98          // ceil(N_NODES / 1024), bucket = dst >> 10

typedef __attribute__((ext_vector_type(8))) short bf16x8;
typedef __attribute__((ext_vector_type(4))) float f32x4;
typedef unsigned long long u64;

__device__ __forceinline__ float b2f_lo(unsigned int u) {
    return __builtin_bit_cast(float, u << 16);
}
__device__ __forceinline__ float b2f_hi(unsigned int u) {
    return __builtin_bit_cast(float, u & 0xFFFF0000u);
}
__device__ __forceinline__ unsigned short f2b(float f) {
    unsigned int u = __builtin_bit_cast(unsigned int, f);
    u += 0x7FFFu + ((u >> 16) & 1u);
    return (unsigned short)(u >> 16);
}

// ---------------- prep: zero scratch + convert weights + convert x, one dispatch ----------------

__global__ __launch_bounds__(256) void prep_kernel(
    const float* __restrict__ x, unsigned short* __restrict__ xb,
    const float* __restrict__ W0, const float* __restrict__ W1_, const float* __restrict__ W2_,
    const float* __restrict__ W3, const float* __restrict__ W4, const float* __restrict__ W5,
    unsigned short* __restrict__ T0, unsigned short* __restrict__ T1_,
    unsigned short* __restrict__ T2_, unsigned short* __restrict__ T3,
    unsigned short* __restrict__ T4, unsigned short* __restrict__ T5,
    uint4* __restrict__ dob4) {
    int blk = blockIdx.x;
    if (blk < 384) {
        const float* W;
        unsigned short* T;
        switch (blk >> 6) {
            case 0: W = W0; T = T0; break;
            case 1: W = W1_; T = T1_; break;
            case 2: W = W2_; T = T2_; break;
            case 3: W = W3; T = T3; break;
            case 4: W = W4; T = T4; break;
            default: W = W5; T = T5; break;
        }
        int i = (blk & 63) * 256 + threadIdx.x;   // 0..16383
        int k = i >> 7, n = i & 127;
        T[n * 128 + k] = f2b(W[i]);               // [k][n] fp32 -> [n][k] bf16
    } else if (blk < 12884) {
        int i = (blk - 384) * 256 + threadIdx.x;  // float4 chunks, 3200000 total
        if (i < 3200000) {
            float4 v = ((const float4*)x)[i];
            ushort4 o;
            o.x = f2b(v.x); o.y = f2b(v.y); o.z = f2b(v.z); o.w = f2b(v.w);
            ((ushort4*)xb)[i] = o;
        }
    } else {
        int i = (blk - 12884) * 256 + threadIdx.x;  // zero d_out scratch head [0, 806144)
        if (i < 50384) {
            uint4 z = {0u, 0u, 0u, 0u};
            dob4[i] = z;
        }
    }
}

// ---------------- CSR build ----------------

__global__ void hist_kernel(const int* __restrict__ dst, int* __restrict__ deg, int n) {
    int i = blockIdx.x * blockDim.x + threadIdx.x;
    if (i < n) atomicAdd(&deg[dst[i]], 1);
}

__global__ __launch_bounds__(256) void block_sum_kernel(const int* __restrict__ deg,
                                                        int* __restrict__ bsum) {
    __shared__ int s[256];
    int i = blockIdx.x * 256 + threadIdx.x;
    int v = (i < N_NODES) ? deg[i] : 0;
    s[threadIdx.x] = v;
    __syncthreads();
#pragma unroll
    for (int d = 128; d > 0; d >>= 1) {
        if (threadIdx.x < d) s[threadIdx.x] += s[threadIdx.x + d];
        __syncthreads();
    }
    if (threadIdx.x == 0) bsum[blockIdx.x] = s[0];
}

__global__ __launch_bounds__(512) void scan_bsum_kernel(const int* __restrict__ bsum,
                                                        int* __restrict__ bpref,
                                                        int* __restrict__ off) {
    __shared__ int s[512];
    int tid = threadIdx.x;
    int v = (tid < SCAN_BLOCKS) ? bsum[tid] : 0;
    s[tid] = v;
    __syncthreads();
#pragma unroll
    for (int d = 1; d < 512; d <<= 1) {
        int t = (tid >= d) ? s[tid - d] : 0;
        __syncthreads();
        s[tid] += t;
        __syncthreads();
    }
    if (tid < SCAN_BLOCKS) bpref[tid] = s[tid] - v;   // exclusive
    if (tid == 0) off[N_NODES] = N_EDGES;
}

__global__ __launch_bounds__(256) void block_scan_kernel(const int* __restrict__ deg,
                                                         const int* __restrict__ bpref,
                                                         int* __restrict__ off) {
    __shared__ int s[256];
    int i = blockIdx.x * 256 + threadIdx.x;
    int tid = threadIdx.x;
    int v = (i < N_NODES) ? deg[i] : 0;
    s[tid] = v;
    __syncthreads();
#pragma unroll
    for (int d = 1; d < 256; d <<= 1) {
        int t = (tid >= d) ? s[tid - d] : 0;
        __syncthreads();
        s[tid] += t;
        __syncthreads();
    }
    if (i < N_NODES) off[i] = bpref[blockIdx.x] + s[tid] - v;   // exclusive
}

// Bin edges into bucket-ordered packed (dst<<32|src) slabs. Slab base = off[b<<10].
__global__ __launch_bounds__(256) void bin_kernel(const int* __restrict__ src,
                                                  const int* __restrict__ dst,
                                                  const int* __restrict__ off,
                                                  int* __restrict__ bcur,
                                                  u64* __restrict__ ebuf) {
    __shared__ int h[NBUCK];
    __shared__ int base[NBUCK];
    int tid = threadIdx.x;
    if (tid < NBUCK) h[tid] = 0;
    __syncthreads();
    int e0 = blockIdx.x * 2048;
    int myd[8], mys[8];
#pragma unroll
    for (int i = 0; i < 8; i++) {
        int e = e0 + tid + i * 256;
        int dv = (e < N_EDGES) ? dst[e] : -1;
        myd[i] = dv;
        mys[i] = (e < N_EDGES) ? src[e] : 0;
        if (dv >= 0) atomicAdd(&h[dv >> 10], 1);
    }
    __syncthreads();
    if (tid < NBUCK) {
        int c = h[tid];
        base[tid] = (c > 0) ? (off[tid << 10] + atomicAdd(&bcur[tid], c)) : 0;
        h[tid] = 0;
    }
    __syncthreads();
#pragma unroll
    for (int i = 0; i < 8; i++) {
        int dv = myd[i];
        if (dv >= 0) {
            int b = dv >> 10;
            int p = base[b] + atomicAdd(&h[b], 1);
            ebuf[p] = ((u64)(unsigned int)dv << 32) | (unsigned int)mys[i];
        }
    }
}

// Sequential bucket-ordered scatter (R5 form — restored after R8's src-banding
// regression: banding spread each csr line's writes over 64 temporal windows,
// 16x write amplification. Sequential emission keeps writes in an L2-resident
// ~64KB window per bucket -> amplification ~1).
__global__ __launch_bounds__(256) void scatter2_kernel(const u64* __restrict__ ebuf,
                                                       const int* __restrict__ off,
                                                       int* __restrict__ cnt,
                                                       int* __restrict__ csr) {
    int i = blockIdx.x * 256 + threadIdx.x;
    if (i < N_EDGES) {
        u64 e = ebuf[i];
        int dv = (int)(e >> 32);
        int p = off[dv] + atomicAdd(&cnt[dv], 1);
        csr[p] = (int)(e & 0xFFFFFFFFu);
    }
}

// ---------------- aggregation: t[i] = x[i] + sum_{j in N_in(i)} x[j]  (bf16 in/out) ----------------

__global__ __launch_bounds__(256) void agg_bf16(const unsigned int* __restrict__ xb,
                                                const int* __restrict__ off,
                                                const int* __restrict__ csr,
                                                unsigned int* __restrict__ t) {
    int node = blockIdx.x * 4 + (threadIdx.x >> 6);
    if (node >= N_NODES) return;
    int lane = threadIdx.x & 63;
    unsigned int v = xb[(size_t)node * 64 + lane];
    float ax = b2f_lo(v), ay = b2f_hi(v);
    int e = off[node + 1];
    int k = off[node];
    for (; k + 4 <= e; k += 4) {
        int n0 = csr[k + 0], n1 = csr[k + 1], n2 = csr[k + 2], n3 = csr[k + 3];
        unsigned int g0 = xb[(size_t)n0 * 64 + lane];
        unsigned int g1 = xb[(size_t)n1 * 64 + lane];
        unsigned int g2 = xb[(size_t)n2 * 64 + lane];
        unsigned int g3 = xb[(size_t)n3 * 64 + lane];
        ax += b2f_lo(g0) + b2f_lo(g1) + b2f_lo(g2) + b2f_lo(g3);
        ay += b2f_hi(g0) + b2f_hi(g1) + b2f_hi(g2) + b2f_hi(g3);
    }
    for (; k < e; k++) {
        unsigned int g = xb[(size_t)csr[k] * 64 + lane];
        ax += b2f_lo(g);
        ay += b2f_hi(g);
    }
    t[(size_t)node * 64 + lane] = (unsigned int)f2b(ax) | ((unsigned int)f2b(ay) << 16);
}

// ---------------- fused MLP: y = relu(relu(t @ W1 + b1) @ W2 + b2) ----------------
// 2 row-strips (32 rows) per wave: one W-fragment load feeds MFMAs of both strips,
// halving per-wave L2 weight traffic (was ~400MB/dispatch). Per-wave LDS 8704 B
// (2 bf16 u-strips; f32 epilogue reuses the same 8704 B region).

template <bool OUT_F32>
__global__ __launch_bounds__(256) void mlp_mfma(const unsigned short* __restrict__ A,
                                                const unsigned short* __restrict__ W1t,
                                                const float* __restrict__ bias1,
                                                const unsigned short* __restrict__ W2t,
                                                const float* __restrict__ bias2,
                                                void* __restrict__ out) {
    __shared__ char smem[4 * 8704];
    int tid = threadIdx.x;
    int wave = tid >> 6, lane = tid & 63;
    int quad = lane >> 4, mr = lane & 15;
    int m_base = blockIdx.x * 128 + wave * 32;
    int m0 = m_base + mr;       if (m0 >= N_NODES) m0 = N_NODES - 1;
    int m1 = m_base + 16 + mr;  if (m1 >= N_NODES) m1 = N_NODES - 1;

    unsigned short* ust = (unsigned short*)(smem + wave * 8704);  // strip0 @0, strip1 @2176 shorts

    // ---- GEMM1: u = relu(t @ W1 + b1), both strips ----
    bf16x8 a0[4], a1[4];
#pragma unroll
    for (int kc = 0; kc < 4; kc++) {
        a0[kc] = *(const bf16x8*)(A + (size_t)m0 * D + kc * 32 + quad * 8);
        a1[kc] = *(const bf16x8*)(A + (size_t)m1 * D + kc * 32 + quad * 8);
    }

    f32x4 acc0[8], acc1[8];
#pragma unroll
    for (int nt = 0; nt < 8; nt++) { acc0[nt] = (f32x4)0.0f; acc1[nt] = (f32x4)0.0f; }
#pragma unroll
    for (int nt = 0; nt < 8; nt++) {
        const unsigned short* wp = W1t + (size_t)(nt * 16 + mr) * D + quad * 8;
#pragma unroll
        for (int kc = 0; kc < 4; kc++) {
            bf16x8 b = *(const bf16x8*)(wp + kc * 32);
            acc0[nt] = __builtin_amdgcn_mfma_f32_16x16x32_bf16(a0[kc], b, acc0[nt], 0, 0, 0);
            acc1[nt] = __builtin_amdgcn_mfma_f32_16x16x32_bf16(a1[kc], b, acc1[nt], 0, 0, 0);
        }
    }
    // C layout: col(n) = mr, row(m in strip) = quad*4 + r
#pragma unroll
    for (int nt = 0; nt < 8; nt++) {
        float bv = bias1[nt * 16 + mr];
#pragma unroll
        for (int r = 0; r < 4; r++) {
            ust[(quad * 4 + r) * 136 + nt * 16 + mr] = f2b(fmaxf(acc0[nt][r] + bv, 0.0f));
            ust[2176 + (quad * 4 + r) * 136 + nt * 16 + mr] = f2b(fmaxf(acc1[nt][r] + bv, 0.0f));
        }
    }

    // ---- GEMM2: y = relu(u @ W2 + b2), both strips ----
#pragma unroll
    for (int kc = 0; kc < 4; kc++) {
        a0[kc] = *(const bf16x8*)&ust[mr * 136 + kc * 32 + quad * 8];
        a1[kc] = *(const bf16x8*)&ust[2176 + mr * 136 + kc * 32 + quad * 8];
    }
#pragma unroll
    for (int nt = 0; nt < 8; nt++) { acc0[nt] = (f32x4)0.0f; acc1[nt] = (f32x4)0.0f; }
#pragma unroll
    for (int nt = 0; nt < 8; nt++) {
        const unsigned short* wp = W2t + (size_t)(nt * 16 + mr) * D + quad * 8;
#pragma unroll
        for (int kc = 0; kc < 4; kc++) {
            bf16x8 b = *(const bf16x8*)(wp + kc * 32);
            acc0[nt] = __builtin_amdgcn_mfma_f32_16x16x32_bf16(a0[kc], b, acc0[nt], 0, 0, 0);
            acc1[nt] = __builtin_amdgcn_mfma_f32_16x16x32_bf16(a1[kc], b, acc1[nt], 0, 0, 0);
        }
    }

    // ---- epilogue: stage each strip in LDS, coalesced store (u-strips dead now) ----
    if (OUT_F32) {
        float* st = (float*)ust;   // 16 x 132 f32 = 8448 B, fits in the 8704 B wave region
        const int S = 132;
        float* op = (float*)out;
#pragma unroll
        for (int s = 0; s < 2; s++) {
#pragma unroll
            for (int nt = 0; nt < 8; nt++) {
                float bv = bias2[nt * 16 + mr];
#pragma unroll
                for (int r = 0; r < 4; r++) {
                    float v = s ? acc1[nt][r] : acc0[nt][r];
                    st[(quad * 4 + r) * S + nt * 16 + mr] = fmaxf(v + bv, 0.0f);
                }
            }
#pragma unroll
            for (int it = 0; it < 8; it++) {
                int linear = lane + it * 64;
                int row = linear >> 5, col = (linear & 31) << 2;
                int gm = m_base + s * 16 + row;
                if (gm < N_NODES) {
                    float4 val = *(float4*)&st[row * S + col];
                    *(float4*)(op + (size_t)gm * D + col) = val;
                }
            }
        }
    } else {
        const int S = 136;
        unsigned short* op = (unsigned short*)out;
#pragma unroll
        for (int s = 0; s < 2; s++) {
            unsigned short* st = ust + s * 2176;
#pragma unroll
            for (int nt = 0; nt < 8; nt++) {
                float bv = bias2[nt * 16 + mr];
#pragma unroll
                for (int r = 0; r < 4; r++) {
                    float v = s ? acc1[nt][r] : acc0[nt][r];
                    st[(quad * 4 + r) * S + nt * 16 + mr] = f2b(fmaxf(v + bv, 0.0f));
                }
            }
#pragma unroll
            for (int it = 0; it < 4; it++) {
                int linear = lane + it * 64;
                int row = linear >> 4, col = (linear & 15) << 3;
                int gm = m_base + s * 16 + row;
                if (gm < N_NODES) {
                    uint4 val = *(uint4*)&st[row * S + col];
                    *(uint4*)(op + (size_t)gm * D + col) = val;
                }
            }
        }
    }
}

// ---------------- launch ----------------

extern "C" void kernel_launch(void* const* d_in, const int* in_sizes, int n_in,
                              void* d_out, int out_size, void* d_ws, size_t ws_size,
                              hipStream_t stream) {
    const float* x = (const float*)d_in[0];
    const int* ei = (const int*)d_in[1];
    const int* srcv = ei;
    const int* dstv = ei + N_EDGES;
    const float* W1[3] = {(const float*)d_in[2], (const float*)d_in[6], (const float*)d_in[10]};
    const float* b1[3] = {(const float*)d_in[3], (const float*)d_in[7], (const float*)d_in[11]};
    const float* W2[3] = {(const float*)d_in[4], (const float*)d_in[8], (const float*)d_in[12]};
    const float* b2[3] = {(const float*)d_in[5], (const float*)d_in[9], (const float*)d_in[13]};

    // ws layout (high-water 58400256):
    char* ws = (char*)d_ws;
    int* off = (int*)ws;                                    // (N+1) ints
    unsigned short* Wt[6];                                  // 6 x 32KB @ 400128
    for (int i = 0; i < 6; i++) Wt[i] = (unsigned short*)(ws + 400128 + i * 32768);
    int* csr = (int*)(ws + 800256);                         // E ints (ends 7200256)
    unsigned short* xb = (unsigned short*)(ws + 7200256);   // N*D bf16 (ends 32800256)
    unsigned short* P  = (unsigned short*)(ws + 32800256);  // N*D bf16 (ends 58400256)

    // d_out scratch (dead before the final MLP overwrites all of d_out):
    char* dob = (char*)d_out;
    int* deg   = (int*)(dob + 4096);        // N ints
    int* cnt2  = (int*)(dob + 404096);      // N ints
    int* bcur  = (int*)(dob + 804096);      // NBUCK ints
    int* bsum  = (int*)(dob + 806912);      // SCAN_BLOCKS ints
    int* bpref = (int*)(dob + 808960);      // SCAN_BLOCKS ints
    u64* ebuf  = (u64*)(dob + 1048576);     // E u64 = 12.8MB

    // --- prep: zero d_out scratch head + convert weights + convert x ---
    prep_kernel<<<13082, 256, 0, stream>>>(
        x, xb,
        W1[0], W2[0], W1[1], W2[1], W1[2], W2[2],
        Wt[0], Wt[1], Wt[2], Wt[3], Wt[4], Wt[5],
        (uint4*)dob);

    // --- CSR build (once; reused by all 3 layers) ---
    hist_kernel<<<(N_EDGES + 255) / 256, 256, 0, stream>>>(dstv, deg, N_EDGES);
    block_sum_kernel<<<SCAN_BLOCKS, 256, 0, stream>>>(deg, bsum);
    scan_bsum_kernel<<<1, 512, 0, stream>>>(bsum, bpref, off);
    block_scan_kernel<<<SCAN_BLOCKS, 256, 0, stream>>>(deg, bpref, off);
    bin_kernel<<<782, 256, 0, stream>>>(srcv, dstv, off, bcur, ebuf);
    scatter2_kernel<<<(N_EDGES + 255) / 256, 256, 0, stream>>>(ebuf, off, cnt2, csr);

    const int agg_grid = 25000;                        // 4 nodes/block
    const int mlp_grid = (N_NODES + 127) / 128;        // 782 (2 strips/wave)

    // layer 0: agg xb->P, mlp P->xb
    agg_bf16<<<agg_grid, 256, 0, stream>>>((const unsigned int*)xb, off, csr, (unsigned int*)P);
    mlp_mfma<false><<<mlp_grid, 256, 0, stream>>>(P, Wt[0], b1[0], Wt[1], b2[0], xb);
    // layer 1
    agg_bf16<<<agg_grid, 256, 0, stream>>>((const unsigned int*)xb, off, csr, (unsigned int*)P);
    mlp_mfma<false><<<mlp_grid, 256, 0, stream>>>(P, Wt[2], b1[1], Wt[3], b2[1], xb);
    // layer 2
    agg_bf16<<<agg_grid, 256, 0, stream>>>((const unsigned int*)xb, off, csr, (unsigned int*)P);
    mlp_mfma<true><<<mlp_grid, 256, 0, stream>>>(P, Wt[4], b1[2], Wt[5], b2[2], d_out);
}